// Round 1
// baseline (219.103 us; speedup 1.0000x reference)
//
#include <hip/hip_runtime.h>
#include <cstdint>
#include <cstddef>

typedef unsigned short u16;
typedef __attribute__((ext_vector_type(8))) short s16x8;
typedef __attribute__((ext_vector_type(8))) u16 u16x8;
typedef __attribute__((ext_vector_type(4))) float f32x4;

#define DEV static __device__ __forceinline__

DEV float b2f(u16 u) { union { unsigned i; float f; } c; c.i = ((unsigned)u) << 16; return c.f; }
DEV u16 f2b(float f) {
  union { float f; unsigned i; } c; c.f = f;
  unsigned r = (c.i + 0x7fffu + ((c.i >> 16) & 1u)) >> 16;
  return (u16)r;
}
DEV float sigm(float x) { return 1.0f / (1.0f + __expf(-x)); }

// ---------------------------------------------------------------------------
// Pack gate weights (f32 in) into concatenated bf16 [N,1536]:
//   WZR rows 0..1023    = [W_xz | W_hz | W_mz]
//   WZR rows 1024..2047 = [W_xr | W_hr | W_mr]
//   WH  rows 0..1023    = [W_xh | W_hh | W_mh]
// plus bf16 copy of W_gamma_h -> WGH [1024,256] (GEMM A weight).
// ---------------------------------------------------------------------------
__global__ __launch_bounds__(256) void pack_w(
    const float* __restrict__ Wxz, const float* __restrict__ Whz, const float* __restrict__ Wmz,
    const float* __restrict__ Wxr, const float* __restrict__ Whr, const float* __restrict__ Wmr,
    const float* __restrict__ Wxh, const float* __restrict__ Whh, const float* __restrict__ Wmh,
    const float* __restrict__ Wgh,
    u16* __restrict__ WZR, u16* __restrict__ WH, u16* __restrict__ WGH)
{
  int t = blockIdx.x * 256 + threadIdx.x;     // 2432*256 threads
  const float* src;
  u16* dst;
  if (t < 589824) {                           // 3072 rows x 192 chunks of 8
    int row = t / 192;
    int col = (t % 192) * 8;
    int rr = row & 1023;
    const float *wx, *wh, *wm;
    if (row < 1024)      { wx = Wxz; wh = Whz; wm = Wmz; }
    else if (row < 2048) { wx = Wxr; wh = Whr; wm = Wmr; }
    else                 { wx = Wxh; wh = Whh; wm = Wmh; }
    if (col < 256)       src = wx + rr * 256 + col;
    else if (col < 1280) src = wh + (size_t)rr * 1024 + (col - 256);
    else                 src = wm + rr * 256 + (col - 1280);
    dst = (row < 2048) ? (WZR + (size_t)row * 1536 + col)
                       : (WH + (size_t)(row - 2048) * 1536 + col);
  } else {                                    // 1024x256 W_gamma_h copy
    int t2 = t - 589824;                      // 32768 threads
    src = Wgh + t2 * 8;
    dst = WGH + t2 * 8;
  }
  f32x4 a = *(const f32x4*)src;
  f32x4 b = *(const f32x4*)(src + 4);
  u16x8 v;
#pragma unroll
  for (int j = 0; j < 4; ++j) { v[j] = f2b(a[j]); v[j + 4] = f2b(b[j]); }
  *(u16x8*)dst = v;
}

// ---------------------------------------------------------------------------
// Elementwise over [B,D]: gamma_x, imputation, x_hat. Writes bf16 x_hat and m
// into X1 (cols 0..255 / 1280..1535), bf16 delta copy, f32 x_last_obs_new.
// ---------------------------------------------------------------------------
__global__ __launch_bounds__(256) void elem_k(
    const float* __restrict__ x, const float* __restrict__ m, const float* __restrict__ delta,
    const float* __restrict__ xlo, const float* __restrict__ x_mean,
    const float* __restrict__ Wgx, const float* __restrict__ bgx,
    u16* __restrict__ X1, u16* __restrict__ Dbf,
    float* __restrict__ out_xlo)
{
  int t = blockIdx.x * 256 + threadIdx.x;     // 262144 threads, 8 elems each
  int row = t >> 5;
  int col = (t & 31) * 8;
  size_t base = (size_t)row * 256 + col;
  u16x8 vxhat, vm16, vd16;
  f32x4 vlnew[2];
#pragma unroll
  for (int half = 0; half < 2; ++half) {
    f32x4 vx = *(const f32x4*)(x + base + half * 4);
    f32x4 vm = *(const f32x4*)(m + base + half * 4);
    f32x4 vd = *(const f32x4*)(delta + base + half * 4);
    f32x4 vl = *(const f32x4*)(xlo + base + half * 4);
    f32x4 vmean = *(const f32x4*)(x_mean + col + half * 4);
    f32x4 vwg = *(const f32x4*)(Wgx + col + half * 4);
    f32x4 vbg = *(const f32x4*)(bgx + col + half * 4);
#pragma unroll
    for (int j = 0; j < 4; ++j) {
      float mf = vm[j];
      float lnew = (mf > 0.5f) ? vx[j] : vl[j];
      vlnew[half][j] = lnew;
      float gx = __expf(-fmaxf(vd[j] * vwg[j] + vbg[j], 0.0f));
      float ximp = gx * lnew + (1.0f - gx) * vmean[j];
      float xhat = mf * vx[j] + (1.0f - mf) * ximp;
      vxhat[half * 4 + j] = f2b(xhat);
      vm16[half * 4 + j] = f2b(mf);
      vd16[half * 4 + j] = f2b(vd[j]);
    }
  }
  size_t r1536 = (size_t)row * 1536;
  *(u16x8*)(X1 + r1536 + col) = vxhat;
  *(u16x8*)(X1 + r1536 + 1280 + col) = vm16;
  *(u16x8*)(Dbf + base) = vd16;
  *(f32x4*)(out_xlo + base) = vlnew[0];
  *(f32x4*)(out_xlo + base + 4) = vlnew[1];
}

// ---------------------------------------------------------------------------
// Pipelined bf16 GEMM: C[M,N] = A[M,K] @ W[N,K]^T.
// BM=256, BN=64*WN, BK=64. Waves 2 x WN, per-wave 128x64 (8m x 4n frags).
// Double-buffered LDS, raw s_barrier + counted s_waitcnt (no __syncthreads
// drain), prefetch issued right after the barrier -> issue-to-wait distance
// = 1 full K-iteration. XOR bank swizzle: linear LDS dest (global_load_lds),
// inverse-swizzled global source, swizzled ds_read (colblk ^= row&7).
// EPI 0: h_decayed = exp(-relu(.+bgh)) * h      -> X1 cols 256..1279 (bf16)
// EPI 1: cols<1024: z=sigmoid -> Z ; cols>=1024: r*hdec -> RH (bf16)
// EPI 2: h_new = (1-z)*hdec + z*tanh(.+bmh)     -> d_out (f32)
//        (EPI2 A-operand: X1 for k<256 & k>=1280, RH for middle cols)
// ---------------------------------------------------------------------------
template<int EPI, int WN>
__global__ __launch_bounds__(128 * WN, WN / 2) void gemm_bt(
    const u16* __restrict__ A, const u16* __restrict__ A2, int K,
    const u16* __restrict__ W,
    const float* __restrict__ bias0, const float* __restrict__ bias1,
    const float* __restrict__ auxf,  // EPI0: h (f32)
    const u16* __restrict__ auxb,    // EPI1/2: X1 (hdec source, bf16)
    const u16* __restrict__ aux2b,   // EPI2: Z (bf16)
    u16* __restrict__ out0b,         // EPI0: X1 ; EPI1: Z
    u16* __restrict__ out1b,         // EPI1: RH
    float* __restrict__ outf)        // EPI2: d_out h_new
{
  constexpr int TPB = 128 * WN;
  constexpr int BN = 64 * WN;
  constexpr int RPR = TPB / 8;        // rows per staging round (8 thr/row)
  constexpr int NRA = 256 / RPR;
  constexpr int NRB = BN / RPR;
  __shared__ alignas(16) u16 As[2][256 * 64];
  __shared__ alignas(16) u16 Bs[2][BN * 64];

  const int tid = threadIdx.x;
  const int lane = tid & 63;
  const int wave = tid >> 6;
  const int wr = wave / WN;           // 0..1
  const int wc = wave % WN;           // 0..WN-1
  const int brow = blockIdx.y * 256;
  const int bcol = blockIdx.x * BN;
  const int NT = K / 64;

  const int slr = lane >> 3;                         // staging row-in-8 (= row&7)
  const int scol = ((lane & 7) ^ slr) * 8;           // inverse-swizzled src col

  f32x4 acc[8][4];
#pragma unroll
  for (int i = 0; i < 8; ++i)
#pragma unroll
    for (int j = 0; j < 4; ++j) { f32x4 z0 = {0.f, 0.f, 0.f, 0.f}; acc[i][j] = z0; }

  auto stage = [&](int kt, int bu) {
    const int k0 = kt * 64;
    const u16* Ab; size_t Astr;
    if constexpr (EPI == 2) {
      if (kt >= 4 && kt < 20) { Ab = A2 + (size_t)brow * 1024 + (k0 - 256); Astr = 1024; }
      else                    { Ab = A + (size_t)brow * 1536 + k0;          Astr = 1536; }
    } else {
      Ab = A + (size_t)brow * (size_t)K + k0; Astr = (size_t)K;
    }
    const u16* Wb = W + (size_t)bcol * (size_t)K + k0;
#pragma unroll
    for (int l = 0; l < NRA; ++l) {
      int rb = l * RPR + wave * 8;
      __builtin_amdgcn_global_load_lds(
          (const __attribute__((address_space(1))) void*)(Ab + (size_t)(rb + slr) * Astr + scol),
          (__attribute__((address_space(3))) void*)(&As[bu][rb * 64]), 16, 0, 0);
    }
#pragma unroll
    for (int l = 0; l < NRB; ++l) {
      int rb = l * RPR + wave * 8;
      __builtin_amdgcn_global_load_lds(
          (const __attribute__((address_space(1))) void*)(Wb + (size_t)(rb + slr) * (size_t)K + scol),
          (__attribute__((address_space(3))) void*)(&Bs[bu][rb * 64]), 16, 0, 0);
    }
  };

  stage(0, 0);

  const int lr = lane & 15, g4 = lane >> 4, l8 = lane & 7;

  for (int kt = 0; kt < NT; ++kt) {
    // tile kt's loads were issued one full iteration ago -> near-zero stall
    asm volatile("s_waitcnt vmcnt(0)" ::: "memory");
    __builtin_amdgcn_s_barrier();
    asm volatile("" ::: "memory");
    if (kt + 1 < NT) stage(kt + 1, (kt + 1) & 1);   // after barrier: race-free
    const u16* as_ = &As[kt & 1][0];
    const u16* bs_ = &Bs[kt & 1][0];
#pragma unroll
    for (int s = 0; s < 2; ++s) {
      s16x8 af[8], bfr[4];
#pragma unroll
      for (int i = 0; i < 8; ++i)
        af[i] = *(const s16x8*)&as_[(wr * 128 + i * 16 + lr) * 64 + (((s * 4 + g4) ^ l8) * 8)];
#pragma unroll
      for (int j = 0; j < 4; ++j)
        bfr[j] = *(const s16x8*)&bs_[(wc * 64 + j * 16 + lr) * 64 + (((s * 4 + g4) ^ l8) * 8)];
      asm volatile("s_waitcnt lgkmcnt(0)" ::: "memory");
      __builtin_amdgcn_sched_barrier(0);
      __builtin_amdgcn_s_setprio(1);
#pragma unroll
      for (int i = 0; i < 8; ++i)
#pragma unroll
        for (int j = 0; j < 4; ++j)
          acc[i][j] = __builtin_amdgcn_mfma_f32_16x16x32_bf16(af[i], bfr[j], acc[i][j], 0, 0, 0);
      __builtin_amdgcn_s_setprio(0);
    }
  }

  // epilogue: C/D layout col=lane&15, row=(lane>>4)*4+q  [verified m89/m91]
  const int row0 = brow + wr * 128 + (lane >> 4) * 4;
  const int col0 = bcol + wc * 64 + (lane & 15);
#pragma unroll
  for (int i = 0; i < 8; ++i) {
#pragma unroll
    for (int j = 0; j < 4; ++j) {
      int c_ = col0 + j * 16;
#pragma unroll
      for (int q = 0; q < 4; ++q) {
        int r_ = row0 + i * 16 + q;
        float v = acc[i][j][q];
        if constexpr (EPI == 0) {
          float p = v + bias0[c_];
          float gh = __expf(-fmaxf(p, 0.0f));
          float hd = gh * auxf[(size_t)r_ * 1024 + c_];
          out0b[(size_t)r_ * 1536 + 256 + c_] = f2b(hd);
        } else if constexpr (EPI == 1) {
          if (c_ < 1024) {
            out0b[(size_t)r_ * 1024 + c_] = f2b(sigm(v + bias0[c_]));
          } else {
            int jc = c_ - 1024;
            float rg = sigm(v + bias1[jc]);
            float hd = b2f(auxb[(size_t)r_ * 1536 + 256 + jc]);
            out1b[(size_t)r_ * 1024 + jc] = f2b(rg * hd);
          }
        } else {
          float ht = tanhf(v + bias0[c_]);
          float zz = b2f(aux2b[(size_t)r_ * 1024 + c_]);
          float hd = b2f(auxb[(size_t)r_ * 1536 + 256 + c_]);
          outf[(size_t)r_ * 1024 + c_] = (1.0f - zz) * hd + zz * ht;
        }
      }
    }
  }
}

// ---------------------------------------------------------------------------
extern "C" void kernel_launch(void* const* d_in, const int* in_sizes, int n_in,
                              void* d_out, int out_size, void* d_ws, size_t ws_size,
                              hipStream_t stream)
{
  const float* x     = (const float*)d_in[0];
  const float* m     = (const float*)d_in[1];
  const float* delta = (const float*)d_in[2];
  const float* h     = (const float*)d_in[3];
  const float* xlo   = (const float*)d_in[4];
  const float* xmean = (const float*)d_in[5];
  const float* Wgx   = (const float*)d_in[6];
  const float* bgx   = (const float*)d_in[7];
  const float* Wgh   = (const float*)d_in[8];
  const float* bgh   = (const float*)d_in[9];
  const float* Wxz   = (const float*)d_in[10];
  const float* Whz   = (const float*)d_in[11];
  const float* Wmz   = (const float*)d_in[12];
  const float* bmz   = (const float*)d_in[13];
  const float* Wxr   = (const float*)d_in[14];
  const float* Whr   = (const float*)d_in[15];
  const float* Wmr   = (const float*)d_in[16];
  const float* bmr   = (const float*)d_in[17];
  const float* Wxh   = (const float*)d_in[18];
  const float* Whh   = (const float*)d_in[19];
  const float* Wmh   = (const float*)d_in[20];
  const float* bmh   = (const float*)d_in[21];

  // workspace (bf16 elems): X1[8192,1536] Z[8192,1024] RH[8192,1024]
  //   WZR[2048,1536] WH[1024,1536] Dbf[8192,256] WGH[1024,256]  ~72.9MB
  u16* X1  = (u16*)d_ws;
  u16* Z   = X1 + (size_t)8192 * 1536;
  u16* RH  = Z  + (size_t)8192 * 1024;
  u16* WZR = RH + (size_t)8192 * 1024;
  u16* WH  = WZR + (size_t)2048 * 1536;
  u16* Dbf = WH + (size_t)1024 * 1536;
  u16* WGH = Dbf + (size_t)8192 * 256;

  float* out_h   = (float*)d_out;
  float* out_xlo = out_h + (size_t)8192 * 1024;

  pack_w<<<2432, 256, 0, stream>>>(Wxz, Whz, Wmz, Wxr, Whr, Wmr, Wxh, Whh, Wmh, Wgh, WZR, WH, WGH);
  elem_k<<<1024, 256, 0, stream>>>(x, m, delta, xlo, xmean, Wgx, bgx, X1, Dbf, out_xlo);
  // GEMM A: gamma_h -> h_decayed into X1[:,256:1280]   (M=8192,N=1024,K=256)
  gemm_bt<0, 2><<<dim3(8, 32), 256, 0, stream>>>(
      Dbf, nullptr, 256, WGH, bgh, nullptr, h, nullptr, nullptr, X1, nullptr, nullptr);
  // GEMM B: z -> Z ; r*h_decayed -> RH                 (M=8192,N=2048,K=1536)
  gemm_bt<1, 4><<<dim3(8, 32), 512, 0, stream>>>(
      X1, nullptr, 1536, WZR, bmz, bmr, nullptr, X1, nullptr, Z, RH, nullptr);
  // GEMM C: h_tilde + final blend -> h_new (f32)       (M=8192,N=1024,K=1536)
  gemm_bt<2, 2><<<dim3(8, 32), 256, 0, stream>>>(
      X1, RH, 1536, WH, bmh, nullptr, nullptr, X1, Z, nullptr, nullptr, out_h);
}

// Round 2
// 168.449 us; speedup vs baseline: 1.3007x; 1.3007x over previous
//
#include <hip/hip_runtime.h>
#include <cstdint>
#include <cstddef>

typedef unsigned short u16;
typedef __attribute__((ext_vector_type(8))) short s16x8;
typedef __attribute__((ext_vector_type(8))) u16 u16x8;
typedef __attribute__((ext_vector_type(4))) float f32x4;

#define DEV static __device__ __forceinline__
#define GPTR(p) (const __attribute__((address_space(1))) void*)(p)
#define LPTR(p) (__attribute__((address_space(3))) void*)(p)

DEV float b2f(u16 u) { union { unsigned i; float f; } c; c.i = ((unsigned)u) << 16; return c.f; }
DEV u16 f2b(float f) {
  union { float f; unsigned i; } c; c.f = f;
  unsigned r = (c.i + 0x7fffu + ((c.i >> 16) & 1u)) >> 16;
  return (u16)r;
}
DEV float sigm(float x) { return 1.0f / (1.0f + __expf(-x)); }

// ---------------------------------------------------------------------------
// Pack gate weights (f32 in) into concatenated bf16 [N,1536]:
//   WZR rows 0..1023    = [W_xz | W_hz | W_mz]
//   WZR rows 1024..2047 = [W_xr | W_hr | W_mr]
//   WH  rows 0..1023    = [W_xh | W_hh | W_mh]
// plus bf16 copy of W_gamma_h -> WGH [1024,256].
// ---------------------------------------------------------------------------
__global__ __launch_bounds__(256) void pack_w(
    const float* __restrict__ Wxz, const float* __restrict__ Whz, const float* __restrict__ Wmz,
    const float* __restrict__ Wxr, const float* __restrict__ Whr, const float* __restrict__ Wmr,
    const float* __restrict__ Wxh, const float* __restrict__ Whh, const float* __restrict__ Wmh,
    const float* __restrict__ Wgh,
    u16* __restrict__ WZR, u16* __restrict__ WH, u16* __restrict__ WGH)
{
  int t = blockIdx.x * 256 + threadIdx.x;
  const float* src;
  u16* dst;
  if (t < 589824) {
    int row = t / 192;
    int col = (t % 192) * 8;
    int rr = row & 1023;
    const float *wx, *wh, *wm;
    if (row < 1024)      { wx = Wxz; wh = Whz; wm = Wmz; }
    else if (row < 2048) { wx = Wxr; wh = Whr; wm = Wmr; }
    else                 { wx = Wxh; wh = Whh; wm = Wmh; }
    if (col < 256)       src = wx + rr * 256 + col;
    else if (col < 1280) src = wh + (size_t)rr * 1024 + (col - 256);
    else                 src = wm + rr * 256 + (col - 1280);
    dst = (row < 2048) ? (WZR + (size_t)row * 1536 + col)
                       : (WH + (size_t)(row - 2048) * 1536 + col);
  } else {
    int t2 = t - 589824;
    src = Wgh + t2 * 8;
    dst = WGH + t2 * 8;
  }
  f32x4 a = *(const f32x4*)src;
  f32x4 b = *(const f32x4*)(src + 4);
  u16x8 v;
#pragma unroll
  for (int j = 0; j < 4; ++j) { v[j] = f2b(a[j]); v[j + 4] = f2b(b[j]); }
  *(u16x8*)dst = v;
}

// ---------------------------------------------------------------------------
// Elementwise over [B,D]: gamma_x, imputation, x_hat -> X1 cols 0..255 and
// 1280..1535 (m), bf16 delta copy, f32 x_last_obs_new.
// ---------------------------------------------------------------------------
__global__ __launch_bounds__(256) void elem_k(
    const float* __restrict__ x, const float* __restrict__ m, const float* __restrict__ delta,
    const float* __restrict__ xlo, const float* __restrict__ x_mean,
    const float* __restrict__ Wgx, const float* __restrict__ bgx,
    u16* __restrict__ X1, u16* __restrict__ Dbf,
    float* __restrict__ out_xlo)
{
  int t = blockIdx.x * 256 + threadIdx.x;
  int row = t >> 5;
  int col = (t & 31) * 8;
  size_t base = (size_t)row * 256 + col;
  u16x8 vxhat, vm16, vd16;
  f32x4 vlnew[2];
#pragma unroll
  for (int half = 0; half < 2; ++half) {
    f32x4 vx = *(const f32x4*)(x + base + half * 4);
    f32x4 vm = *(const f32x4*)(m + base + half * 4);
    f32x4 vd = *(const f32x4*)(delta + base + half * 4);
    f32x4 vl = *(const f32x4*)(xlo + base + half * 4);
    f32x4 vmean = *(const f32x4*)(x_mean + col + half * 4);
    f32x4 vwg = *(const f32x4*)(Wgx + col + half * 4);
    f32x4 vbg = *(const f32x4*)(bgx + col + half * 4);
#pragma unroll
    for (int j = 0; j < 4; ++j) {
      float mf = vm[j];
      float lnew = (mf > 0.5f) ? vx[j] : vl[j];
      vlnew[half][j] = lnew;
      float gx = __expf(-fmaxf(vd[j] * vwg[j] + vbg[j], 0.0f));
      float ximp = gx * lnew + (1.0f - gx) * vmean[j];
      float xhat = mf * vx[j] + (1.0f - mf) * ximp;
      vxhat[half * 4 + j] = f2b(xhat);
      vm16[half * 4 + j] = f2b(mf);
      vd16[half * 4 + j] = f2b(vd[j]);
    }
  }
  size_t r1536 = (size_t)row * 1536;
  *(u16x8*)(X1 + r1536 + col) = vxhat;
  *(u16x8*)(X1 + r1536 + 1280 + col) = vm16;
  *(u16x8*)(Dbf + base) = vd16;
  *(f32x4*)(out_xlo + base) = vlnew[0];
  *(f32x4*)(out_xlo + base + 4) = vlnew[1];
}

// ---------------------------------------------------------------------------
// 8-phase-style pipelined bf16 GEMM (m201 template port, plain HIP):
//   C[M,N] = A[M,K] @ W[N,K]^T.   BN=256, BM=MF*32, BK=64, 8 waves (2M x 4N),
//   per-wave MF x 4 frags (MF=8 -> 128x64, MF=4 -> 64x64).
// Per K-tile: 2*(MF/4) phases, each = {ds_read 4-8 frags | stage burst |
//   s_barrier | lgkmcnt(0) | setprio(1) 16 MFMA setprio(0) | s_barrier}.
// Wave-self staging: each wave stages exactly the A-half/B-half it reads for
// tile t+1 during phases 0-1 of tile t; per-tile vmcnt(0) sits 2-3 phases
// after issue (counted-wait effect, no cross-wave DMA publish hazard).
// LDS XOR swizzle: linear LDS dest + inverse-swizzled global source +
// swizzled ds_read (chunk ^= row&7).  XCD-bijective block swizzle (nwg=256).
// EPI 0: h_decayed = exp(-relu(.+bgh)) * h      -> X1 cols 256..1279 (bf16)
// EPI 1: cols<1024: z=sigmoid -> Z ; cols>=1024: r*hdec -> RH (bf16)
// EPI 2: h_new = (1-z)*hdec + z*tanh(.+bmh)     -> d_out (f32)
//        (EPI2 A-operand: X1 for k<256 & k>=1280, RH for middle cols)
// ---------------------------------------------------------------------------
template<int EPI, int MF>
__global__ __launch_bounds__(512, 2) void gemm_bt(
    const u16* __restrict__ A, const u16* __restrict__ A2, int K,
    const u16* __restrict__ W,
    const float* __restrict__ bias0, const float* __restrict__ bias1,
    const float* __restrict__ auxf,  // EPI0: h (f32)
    const u16* __restrict__ auxb,    // EPI1/2: X1 (hdec source, bf16)
    const u16* __restrict__ aux2b,   // EPI2: Z (bf16)
    u16* __restrict__ out0b,         // EPI0: X1 ; EPI1: Z
    u16* __restrict__ out1b,         // EPI1: RH
    float* __restrict__ outf)        // EPI2: d_out h_new
{
  constexpr int BM = MF * 32;
  constexpr int GX = (MF == 8) ? 8 : 4;    // gridDim.x (pow2), nwg must be 256
  constexpr int LA = BM / 64;              // per-thread A stage loads
  __shared__ alignas(16) u16 As[2][BM * 64];
  __shared__ alignas(16) u16 Bs[2][256 * 64];

  const int tid = threadIdx.x;
  const int lane = tid & 63;
  const int wave = tid >> 6;
  const int wr = wave >> 2;                // 0..1 (M)
  const int wc = wave & 3;                 // 0..3 (N)

  // bijective XCD swizzle: 32 consecutive logical blocks per XCD
  const int d = blockIdx.y * GX + blockIdx.x;
  const int L = ((d & 7) << 5) | (d >> 3);
  const int brow = (L >> ((GX == 8) ? 3 : 2)) * BM;
  const int bcol = (L & (GX - 1)) * 256;
  const int NT = K / 64;

  const int slr = lane >> 3;               // staging sub-row (= row & 7)
  const int scol = ((lane & 7) ^ slr) * 8; // inverse-swizzled source chunk
  const int lr = lane & 15, g4 = lane >> 4, l8 = lane & 7;

  f32x4 acc[MF][4];
#pragma unroll
  for (int i = 0; i < MF; ++i)
#pragma unroll
    for (int j = 0; j < 4; ++j) { f32x4 z0 = {0.f, 0.f, 0.f, 0.f}; acc[i][j] = z0; }

  // wave stages its own A-half (rows wr*BM/2 ..) with the 3 other same-wr waves
  auto stageA = [&](int kt, int bu) {
    const int k0 = kt * 64;
    const u16* Ab; size_t Astr; int co = k0;
    if constexpr (EPI == 2) {
      if (kt >= 4 && kt < 20) { Ab = A2; Astr = 1024; co = k0 - 256; }
      else                    { Ab = A;  Astr = 1536; }
    } else { Ab = A; Astr = (size_t)K; }
#pragma unroll
    for (int j = 0; j < LA; ++j) {
      int rh = (j * 4 + wc) * 8;           // row-block within the half
      int grow = brow + wr * (BM / 2) + rh + slr;
      __builtin_amdgcn_global_load_lds(
          GPTR(Ab + (size_t)grow * Astr + co + scol),
          LPTR(&As[bu][(wr * (BM / 2) + rh) * 64]), 16, 0, 0);
    }
  };
  // wave stages its own B-half (rows (wc>>1)*128 ..) with 3 partner waves
  auto stageB = [&](int kt, int bu) {
    const int k0 = kt * 64;
    const int gw = wr * 2 + (wc & 1), hb = wc >> 1;
#pragma unroll
    for (int j = 0; j < 4; ++j) {
      int rh = (j * 4 + gw) * 8;
      int grow = bcol + hb * 128 + rh + slr;
      __builtin_amdgcn_global_load_lds(
          GPTR(W + (size_t)grow * (size_t)K + k0 + scol),
          LPTR(&Bs[bu][(hb * 128 + rh) * 64]), 16, 0, 0);
    }
  };

  // prologue: tile 0 staged + published
  stageA(0, 0); stageB(0, 0);
  asm volatile("s_waitcnt vmcnt(0)" ::: "memory");
  __builtin_amdgcn_s_barrier();

  for (int kt = 0; kt < NT; ++kt) {
    const int bu = kt & 1;
    const u16* as_ = &As[bu][0];
    const u16* bs_ = &Bs[bu][0];
    s16x8 bfr[4];
#pragma unroll
    for (int ks = 0; ks < 2; ++ks) {
#pragma unroll
      for (int ih = 0; ih < MF / 4; ++ih) {
        const int ph = ks * (MF / 4) + ih;
        const int kc = ((ks * 4 + g4) ^ l8) * 8;
        s16x8 af[4];
        if (ih == 0)
#pragma unroll
          for (int j = 0; j < 4; ++j)
            bfr[j] = *(const s16x8*)&bs_[(wc * 64 + j * 16 + lr) * 64 + kc];
#pragma unroll
        for (int ii = 0; ii < 4; ++ii)
          af[ii] = *(const s16x8*)&as_[(wr * (BM / 2) + (ih * 4 + ii) * 16 + lr) * 64 + kc];
        if (kt + 1 < NT) {
          if (ph == 0) { stageA(kt + 1, bu ^ 1); if (MF == 4) stageB(kt + 1, bu ^ 1); }
          else if (ph == 1 && MF == 8) stageB(kt + 1, bu ^ 1);
        }
        __builtin_amdgcn_sched_barrier(0);
        if (ph == 2 * (MF / 4) - 1 && kt + 1 < NT)
          asm volatile("s_waitcnt vmcnt(0)" ::: "memory");  // own t+1 stages, issued 1-3 phases ago
        __builtin_amdgcn_s_barrier();
        asm volatile("s_waitcnt lgkmcnt(0)" ::: "memory");
        __builtin_amdgcn_sched_barrier(0);
        __builtin_amdgcn_s_setprio(1);
#pragma unroll
        for (int ii = 0; ii < 4; ++ii)
#pragma unroll
          for (int j = 0; j < 4; ++j)
            acc[ih * 4 + ii][j] = __builtin_amdgcn_mfma_f32_16x16x32_bf16(
                af[ii], bfr[j], acc[ih * 4 + ii][j], 0, 0, 0);
        __builtin_amdgcn_s_setprio(0);
        __builtin_amdgcn_sched_barrier(0);
        __builtin_amdgcn_s_barrier();
      }
    }
  }

  // epilogue: C/D layout col=lane&15, row=(lane>>4)*4+q  [verified m89/m91]
  const int row0 = brow + wr * (MF * 16) + g4 * 4;
  const int col0 = bcol + wc * 64 + lr;
#pragma unroll
  for (int i = 0; i < MF; ++i) {
#pragma unroll
    for (int j = 0; j < 4; ++j) {
      int c_ = col0 + j * 16;
#pragma unroll
      for (int q = 0; q < 4; ++q) {
        int r_ = row0 + i * 16 + q;
        float v = acc[i][j][q];
        if constexpr (EPI == 0) {
          float p = v + bias0[c_];
          float gh = __expf(-fmaxf(p, 0.0f));
          float hd = gh * auxf[(size_t)r_ * 1024 + c_];
          out0b[(size_t)r_ * 1536 + 256 + c_] = f2b(hd);
        } else if constexpr (EPI == 1) {
          if (c_ < 1024) {
            out0b[(size_t)r_ * 1024 + c_] = f2b(sigm(v + bias0[c_]));
          } else {
            int jc = c_ - 1024;
            float rg = sigm(v + bias1[jc]);
            float hd = b2f(auxb[(size_t)r_ * 1536 + 256 + jc]);
            out1b[(size_t)r_ * 1024 + jc] = f2b(rg * hd);
          }
        } else {
          float ht = tanhf(v + bias0[c_]);
          float zz = b2f(aux2b[(size_t)r_ * 1024 + c_]);
          float hd = b2f(auxb[(size_t)r_ * 1536 + 256 + c_]);
          outf[(size_t)r_ * 1024 + c_] = (1.0f - zz) * hd + zz * ht;
        }
      }
    }
  }
}

// ---------------------------------------------------------------------------
extern "C" void kernel_launch(void* const* d_in, const int* in_sizes, int n_in,
                              void* d_out, int out_size, void* d_ws, size_t ws_size,
                              hipStream_t stream)
{
  const float* x     = (const float*)d_in[0];
  const float* m     = (const float*)d_in[1];
  const float* delta = (const float*)d_in[2];
  const float* h     = (const float*)d_in[3];
  const float* xlo   = (const float*)d_in[4];
  const float* xmean = (const float*)d_in[5];
  const float* Wgx   = (const float*)d_in[6];
  const float* bgx   = (const float*)d_in[7];
  const float* Wgh   = (const float*)d_in[8];
  const float* bgh   = (const float*)d_in[9];
  const float* Wxz   = (const float*)d_in[10];
  const float* Whz   = (const float*)d_in[11];
  const float* Wmz   = (const float*)d_in[12];
  const float* bmz   = (const float*)d_in[13];
  const float* Wxr   = (const float*)d_in[14];
  const float* Whr   = (const float*)d_in[15];
  const float* Wmr   = (const float*)d_in[16];
  const float* bmr   = (const float*)d_in[17];
  const float* Wxh   = (const float*)d_in[18];
  const float* Whh   = (const float*)d_in[19];
  const float* Wmh   = (const float*)d_in[20];
  const float* bmh   = (const float*)d_in[21];

  // workspace (bf16 elems): X1[8192,1536] Z[8192,1024] RH[8192,1024]
  //   WZR[2048,1536] WH[1024,1536] Dbf[8192,256] WGH[1024,256]  ~72.9MB
  u16* X1  = (u16*)d_ws;
  u16* Z   = X1 + (size_t)8192 * 1536;
  u16* RH  = Z  + (size_t)8192 * 1024;
  u16* WZR = RH + (size_t)8192 * 1024;
  u16* WH  = WZR + (size_t)2048 * 1536;
  u16* Dbf = WH + (size_t)1024 * 1536;
  u16* WGH = Dbf + (size_t)8192 * 256;

  float* out_h   = (float*)d_out;
  float* out_xlo = out_h + (size_t)8192 * 1024;

  pack_w<<<2432, 256, 0, stream>>>(Wxz, Whz, Wmz, Wxr, Whr, Wmr, Wxh, Whh, Wmh, Wgh, WZR, WH, WGH);
  elem_k<<<1024, 256, 0, stream>>>(x, m, delta, xlo, xmean, Wgx, bgx, X1, Dbf, out_xlo);
  // GEMM A: gamma_h -> h_decayed into X1[:,256:1280]   (M=8192,N=1024,K=256)
  gemm_bt<0, 4><<<dim3(4, 64), 512, 0, stream>>>(
      Dbf, nullptr, 256, WGH, bgh, nullptr, h, nullptr, nullptr, X1, nullptr, nullptr);
  // GEMM B: z -> Z ; r*h_decayed -> RH                 (M=8192,N=2048,K=1536)
  gemm_bt<1, 8><<<dim3(8, 32), 512, 0, stream>>>(
      X1, nullptr, 1536, WZR, bmz, bmr, nullptr, X1, nullptr, Z, RH, nullptr);
  // GEMM C: h_tilde + final blend -> h_new (f32)       (M=8192,N=1024,K=1536)
  gemm_bt<2, 4><<<dim3(4, 64), 512, 0, stream>>>(
      X1, RH, 1536, WH, bmh, nullptr, nullptr, X1, Z, nullptr, nullptr, out_h);
}